// Round 8
// baseline (84.235 us; speedup 1.0000x reference)
//
#include <hip/hip_runtime.h>
#include <hip/hip_bf16.h>

// Problem: B=16, N=256, F=64, H=64
// out[b,i,j] = (i==j) ? 1 : sigmoid( sum_h relu(a[b,i,h]+c[b,j,h]) * w2[h] + b2 )
// a = hs @ w1[:, :64]^T + b1, c = hs @ w1[:, 64:]^T
//
// Round-8: two kernels (r6 structure, best so far). Pair kernel reworked for
// latency: 512-thread blocks (2 waves/SIMD instead of 1) + explicit register
// double-buffering so LDS-read latency hides under the previous iteration's
// FMAs instead of a serial waitcnt stall (r5 counters: VALUBusy 26%).

#define Nn 256
#define Fd 64
#define Hd 64

// ---------------- prep: a = hs@w1a^T + b1, c = hs@w1c^T (r6, proven) ----------------
__global__ __launch_bounds__(256) void prep_kernel(
    const float* __restrict__ hs, const float* __restrict__ w1,
    const float* __restrict__ b1,
    float* __restrict__ a_, float* __restrict__ c_) {
  __shared__ float4 hs4s[16][16];

  const int t  = threadIdx.x;
  const int r0 = blockIdx.x * 16;
  const int hout0 = blockIdx.y * 32;

  {
    const int rr = t >> 4, ff = t & 15;
    hs4s[rr][ff ^ rr] = ((const float4*)(hs + (size_t)r0 * Fd))[t];
  }
  __syncthreads();

  const int r  = t & 15;
  const int hl = (t >> 4) * 2;
  const bool isA = (hout0 < Hd);
  const int hA = hout0 + hl - (isA ? 0 : Hd);
  const float* w1base = w1 + (isA ? 0 : Fd);
  const float4* w1r0 = (const float4*)(w1base + (size_t)(hA + 0) * (2 * Fd));
  const float4* w1r1 = (const float4*)(w1base + (size_t)(hA + 1) * (2 * Fd));

  float acc0 = 0.f, acc1 = 0.f;
#pragma unroll
  for (int f4 = 0; f4 < 16; ++f4) {
    const float4 x  = hs4s[r][f4 ^ r];
    const float4 u0 = w1r0[f4];
    const float4 u1 = w1r1[f4];
    acc0 = fmaf(x.x, u0.x, acc0); acc0 = fmaf(x.y, u0.y, acc0);
    acc0 = fmaf(x.z, u0.z, acc0); acc0 = fmaf(x.w, u0.w, acc0);
    acc1 = fmaf(x.x, u1.x, acc1); acc1 = fmaf(x.y, u1.y, acc1);
    acc1 = fmaf(x.z, u1.z, acc1); acc1 = fmaf(x.w, u1.w, acc1);
  }

  float2 res;
  if (isA) {
    res.x = acc0 + b1[hA];
    res.y = acc1 + b1[hA + 1];
    *(float2*)(a_ + (size_t)(r0 + r) * Hd + hA) = res;
  } else {
    res.x = acc0; res.y = acc1;
    *(float2*)(c_ + (size_t)(r0 + r) * Hd + hA) = res;
  }
}

// ---------------- pair: 64x64 tile, 512 threads, 2x4 outputs/thread ----------------
// thread: jt = t&15 (j = j0+jt*4+v), it = t>>4 in [0,32) (i = i0+it*2+u).
// Swizzle col = q ^ ((row>>2)&15): cc-reads 2-way (free), aa-reads broadcast.
// Register double-buffer: h4+1's loads issue before h4's FMAs.
__global__ __launch_bounds__(512) void pair_kernel(
    const float* __restrict__ a_, const float* __restrict__ c_,
    const float* __restrict__ w2, const float* __restrict__ b2,
    float* __restrict__ out) {
  __shared__ float4 aT4[64][16];
  __shared__ float4 cT4[64][16];
  __shared__ float4 w2s4[16];

  const int t  = threadIdx.x;
  const int b  = blockIdx.z;
  const int i0 = blockIdx.y * 64;
  const int j0 = blockIdx.x * 64;

  // stage 64x64 a- and c-tiles (16 KB each), coalesced, swizzled
#pragma unroll
  for (int p = 0; p < 2; ++p) {
    const int k = t + 512 * p;           // 0..1023
    const int rr = k >> 4, q = k & 15;
    const int cs = q ^ ((rr >> 2) & 15);
    aT4[rr][cs] = ((const float4*)(a_ + (size_t)(b * Nn + i0) * Hd))[k];
    cT4[rr][cs] = ((const float4*)(c_ + (size_t)(b * Nn + j0) * Hd))[k];
  }
  if (t < 16) w2s4[t] = ((const float4*)w2)[t];
  __syncthreads();

  const int jt = t & 15;
  const int it = t >> 4;        // 0..31
  const int ib = it * 2;
  const int jb = jt * 4;
  const int sa = (ib >> 2) & 15;   // aa xor mask (uniform per 4 lanesets)
  const int sc = jt;               // cc xor mask

  float acc[2][4];
#pragma unroll
  for (int u = 0; u < 2; ++u)
#pragma unroll
    for (int v = 0; v < 4; ++v) acc[u][v] = 0.f;

  // software pipeline: current regs + next regs
  float4 aa[2], cc[4], ww;
#pragma unroll
  for (int u = 0; u < 2; ++u) aa[u] = aT4[ib + u][0 ^ sa];
#pragma unroll
  for (int v = 0; v < 4; ++v) cc[v] = cT4[jb + v][0 ^ sc];
  ww = w2s4[0];

#pragma unroll
  for (int h4 = 0; h4 < 16; ++h4) {
    float4 naa[2], ncc[4], nww;
    if (h4 < 15) {
      const int n = h4 + 1;
#pragma unroll
      for (int u = 0; u < 2; ++u) naa[u] = aT4[ib + u][n ^ sa];
#pragma unroll
      for (int v = 0; v < 4; ++v) ncc[v] = cT4[jb + v][n ^ sc];
      nww = w2s4[n];
    }

#pragma unroll
    for (int u = 0; u < 2; ++u)
#pragma unroll
      for (int v = 0; v < 4; ++v) {
        acc[u][v] = fmaf(fmaxf(aa[u].x + cc[v].x, 0.f), ww.x, acc[u][v]);
        acc[u][v] = fmaf(fmaxf(aa[u].y + cc[v].y, 0.f), ww.y, acc[u][v]);
        acc[u][v] = fmaf(fmaxf(aa[u].z + cc[v].z, 0.f), ww.z, acc[u][v]);
        acc[u][v] = fmaf(fmaxf(aa[u].w + cc[v].w, 0.f), ww.w, acc[u][v]);
      }

    if (h4 < 15) {
#pragma unroll
      for (int u = 0; u < 2; ++u) aa[u] = naa[u];
#pragma unroll
      for (int v = 0; v < 4; ++v) cc[v] = ncc[v];
      ww = nww;
    }
  }

  const float bias2 = b2[0];
#pragma unroll
  for (int u = 0; u < 2; ++u) {
    const int i = i0 + ib + u;
    float4 o;
    o.x = (i == j0 + jb + 0) ? 1.0f : 1.f / (1.f + __expf(-(acc[u][0] + bias2)));
    o.y = (i == j0 + jb + 1) ? 1.0f : 1.f / (1.f + __expf(-(acc[u][1] + bias2)));
    o.z = (i == j0 + jb + 2) ? 1.0f : 1.f / (1.f + __expf(-(acc[u][2] + bias2)));
    o.w = (i == j0 + jb + 3) ? 1.0f : 1.f / (1.f + __expf(-(acc[u][3] + bias2)));
    ((float4*)(out + (size_t)(b * Nn + i) * Nn + j0))[jt] = o;
  }
}

extern "C" void kernel_launch(void* const* d_in, const int* in_sizes, int n_in,
                              void* d_out, int out_size, void* d_ws, size_t ws_size,
                              hipStream_t stream) {
  const float* hs = (const float*)d_in[0];
  const float* w1 = (const float*)d_in[1];
  const float* b1 = (const float*)d_in[2];
  const float* w2 = (const float*)d_in[3];
  const float* b2 = (const float*)d_in[4];
  float* out = (float*)d_out;

  float* a_ws = (float*)d_ws;                  // 4096*64 floats = 1 MB
  float* c_ws = a_ws + (size_t)4096 * Hd;      // 1 MB

  dim3 pgrid(4096 / 16, 4);                    // 1024 blocks
  prep_kernel<<<pgrid, 256, 0, stream>>>(hs, w1, b1, a_ws, c_ws);

  dim3 qgrid(Nn / 64, Nn / 64, 16);            // 256 blocks = 1/CU, 8 waves
  pair_kernel<<<qgrid, 512, 0, stream>>>(a_ws, c_ws, w2, b2, out);
}

// Round 9
// 25.460 us; speedup vs baseline: 3.3085x; 3.3085x over previous
//
#include <hip/hip_runtime.h>
#include <hip/hip_bf16.h>

// Problem: B=16, N=256, F=64, H=64
// out[b,i,j] = (i==j) ? 1 : sigmoid( sum_h relu(a[b,i,h]+c[b,j,h]) * w2[h] + b2 )
// a = hs @ w1[:, :64]^T + b1, c = hs @ w1[:, 64:]^T
//
// Round-9: r8's 512-thread pair spilled (VGPR capped at 128 -> 150 MB scratch
// traffic, 89 us). Same two ideas, spill-safe: 256-thread blocks (no cap),
// 2 waves/SIMD via 512 blocks (32x64 tiles, 8 outputs/thread), register
// double-buffer for LDS latency hiding.

#define Nn 256
#define Fd 64
#define Hd 64

// ---------------- prep: a = hs@w1a^T + b1, c = hs@w1c^T (r6, proven) ----------------
__global__ __launch_bounds__(256) void prep_kernel(
    const float* __restrict__ hs, const float* __restrict__ w1,
    const float* __restrict__ b1,
    float* __restrict__ a_, float* __restrict__ c_) {
  __shared__ float4 hs4s[16][16];

  const int t  = threadIdx.x;
  const int r0 = blockIdx.x * 16;
  const int hout0 = blockIdx.y * 32;

  {
    const int rr = t >> 4, ff = t & 15;
    hs4s[rr][ff ^ rr] = ((const float4*)(hs + (size_t)r0 * Fd))[t];
  }
  __syncthreads();

  const int r  = t & 15;
  const int hl = (t >> 4) * 2;
  const bool isA = (hout0 < Hd);
  const int hA = hout0 + hl - (isA ? 0 : Hd);
  const float* w1base = w1 + (isA ? 0 : Fd);
  const float4* w1r0 = (const float4*)(w1base + (size_t)(hA + 0) * (2 * Fd));
  const float4* w1r1 = (const float4*)(w1base + (size_t)(hA + 1) * (2 * Fd));

  float acc0 = 0.f, acc1 = 0.f;
#pragma unroll
  for (int f4 = 0; f4 < 16; ++f4) {
    const float4 x  = hs4s[r][f4 ^ r];
    const float4 u0 = w1r0[f4];
    const float4 u1 = w1r1[f4];
    acc0 = fmaf(x.x, u0.x, acc0); acc0 = fmaf(x.y, u0.y, acc0);
    acc0 = fmaf(x.z, u0.z, acc0); acc0 = fmaf(x.w, u0.w, acc0);
    acc1 = fmaf(x.x, u1.x, acc1); acc1 = fmaf(x.y, u1.y, acc1);
    acc1 = fmaf(x.z, u1.z, acc1); acc1 = fmaf(x.w, u1.w, acc1);
  }

  float2 res;
  if (isA) {
    res.x = acc0 + b1[hA];
    res.y = acc1 + b1[hA + 1];
    *(float2*)(a_ + (size_t)(r0 + r) * Hd + hA) = res;
  } else {
    res.x = acc0; res.y = acc1;
    *(float2*)(c_ + (size_t)(r0 + r) * Hd + hA) = res;
  }
}

// ---------------- pair: 32x64 tile, 256 threads, 2x4 outputs/thread ----------------
// 512 blocks = 2 blocks/CU = 8 waves/CU = 2 waves/SIMD.
// thread: jt = t&15 (j = j0+jt*4+v), it = t>>4 (i = i0+it*2+u).
// Swizzle col = q ^ ((row>>2)&15): cc-reads 2-way (free), aa-reads broadcast.
__global__ __launch_bounds__(256) void pair_kernel(
    const float* __restrict__ a_, const float* __restrict__ c_,
    const float* __restrict__ w2, const float* __restrict__ b2,
    float* __restrict__ out) {
  __shared__ float4 aT4[32][16];   // 8 KB
  __shared__ float4 cT4[64][16];   // 16 KB
  __shared__ float4 w2s4[16];

  const int t  = threadIdx.x;
  const int b  = blockIdx.z;
  const int i0 = blockIdx.y * 32;
  const int j0 = blockIdx.x * 64;

  // stage 32-row a-tile (512 f4) and 64-row c-tile (1024 f4), swizzled
#pragma unroll
  for (int p = 0; p < 2; ++p) {
    const int k = t + 256 * p;
    const int rr = k >> 4, q = k & 15;
    aT4[rr][q ^ ((rr >> 2) & 15)] =
        ((const float4*)(a_ + (size_t)(b * Nn + i0) * Hd))[k];
  }
#pragma unroll
  for (int p = 0; p < 4; ++p) {
    const int k = t + 256 * p;
    const int rr = k >> 4, q = k & 15;
    cT4[rr][q ^ ((rr >> 2) & 15)] =
        ((const float4*)(c_ + (size_t)(b * Nn + j0) * Hd))[k];
  }
  if (t < 16) w2s4[t] = ((const float4*)w2)[t];
  __syncthreads();

  const int jt = t & 15;
  const int it = t >> 4;           // 0..15
  const int ib = it * 2;
  const int jb = jt * 4;
  const int sa = it >> 1;          // aa xor mask: ((ib+u)>>2)&15 == it>>1
  const int sc = jt;               // cc xor mask

  float acc[2][4];
#pragma unroll
  for (int u = 0; u < 2; ++u)
#pragma unroll
    for (int v = 0; v < 4; ++v) acc[u][v] = 0.f;

  // software pipeline: preload h4=0
  float4 aa[2], cc[4], ww;
#pragma unroll
  for (int u = 0; u < 2; ++u) aa[u] = aT4[ib + u][0 ^ sa];
#pragma unroll
  for (int v = 0; v < 4; ++v) cc[v] = cT4[jb + v][0 ^ sc];
  ww = w2s4[0];

#pragma unroll
  for (int h4 = 0; h4 < 16; ++h4) {
    float4 naa[2], ncc[4], nww;
    if (h4 < 15) {
      const int n = h4 + 1;
#pragma unroll
      for (int u = 0; u < 2; ++u) naa[u] = aT4[ib + u][n ^ sa];
#pragma unroll
      for (int v = 0; v < 4; ++v) ncc[v] = cT4[jb + v][n ^ sc];
      nww = w2s4[n];
    }

#pragma unroll
    for (int u = 0; u < 2; ++u)
#pragma unroll
      for (int v = 0; v < 4; ++v) {
        acc[u][v] = fmaf(fmaxf(aa[u].x + cc[v].x, 0.f), ww.x, acc[u][v]);
        acc[u][v] = fmaf(fmaxf(aa[u].y + cc[v].y, 0.f), ww.y, acc[u][v]);
        acc[u][v] = fmaf(fmaxf(aa[u].z + cc[v].z, 0.f), ww.z, acc[u][v]);
        acc[u][v] = fmaf(fmaxf(aa[u].w + cc[v].w, 0.f), ww.w, acc[u][v]);
      }

    if (h4 < 15) {
#pragma unroll
      for (int u = 0; u < 2; ++u) aa[u] = naa[u];
#pragma unroll
      for (int v = 0; v < 4; ++v) cc[v] = ncc[v];
      ww = nww;
    }
  }

  const float bias2 = b2[0];
#pragma unroll
  for (int u = 0; u < 2; ++u) {
    const int i = i0 + ib + u;
    float4 o;
    o.x = (i == j0 + jb + 0) ? 1.0f : 1.f / (1.f + __expf(-(acc[u][0] + bias2)));
    o.y = (i == j0 + jb + 1) ? 1.0f : 1.f / (1.f + __expf(-(acc[u][1] + bias2)));
    o.z = (i == j0 + jb + 2) ? 1.0f : 1.f / (1.f + __expf(-(acc[u][2] + bias2)));
    o.w = (i == j0 + jb + 3) ? 1.0f : 1.f / (1.f + __expf(-(acc[u][3] + bias2)));
    ((float4*)(out + (size_t)(b * Nn + i) * Nn + j0))[jt] = o;
  }
}

extern "C" void kernel_launch(void* const* d_in, const int* in_sizes, int n_in,
                              void* d_out, int out_size, void* d_ws, size_t ws_size,
                              hipStream_t stream) {
  const float* hs = (const float*)d_in[0];
  const float* w1 = (const float*)d_in[1];
  const float* b1 = (const float*)d_in[2];
  const float* w2 = (const float*)d_in[3];
  const float* b2 = (const float*)d_in[4];
  float* out = (float*)d_out;

  float* a_ws = (float*)d_ws;                  // 4096*64 floats = 1 MB
  float* c_ws = a_ws + (size_t)4096 * Hd;      // 1 MB

  dim3 pgrid(4096 / 16, 4);                    // 1024 blocks
  prep_kernel<<<pgrid, 256, 0, stream>>>(hs, w1, b1, a_ws, c_ws);

  dim3 qgrid(Nn / 64, Nn / 32, 16);            // 4 x 8 x 16 = 512 blocks
  pair_kernel<<<qgrid, 256, 0, stream>>>(a_ws, c_ws, w2, b2, out);
}

// Round 11
// 19.187 us; speedup vs baseline: 4.3902x; 1.3270x over previous
//
#include <hip/hip_runtime.h>
#include <hip/hip_bf16.h>
#include <hip/hip_fp16.h>

// Problem: B=16, N=256, F=64, H=64
// out[b,i,j] = (i==j) ? 1 : sigmoid( sum_h relu(a[b,i,h]+c[b,j,h]) * w2[h] + b2 )
// a = hs @ w1[:, :64]^T + b1, c = hs @ w1[:, 64:]^T
//
// Round-11: same theory as r10 (f16 pair path: half the LDS instrs, half the
// VALU via pk_add/pk_max/dot2). Fix: use clang _Float16 ext-vector ops
// (+, __builtin_elementwise_max) instead of __hadd2/__hmax2 (ROCm 7.2
// overload clash with bf16).

#define Nn 256
#define Fd 64
#define Hd 64

typedef _Float16 h2v __attribute__((ext_vector_type(2)));
union H2 { h2v v; unsigned int u; };

// ---------------- prep: a = hs@w1a^T + b1, c = hs@w1c^T -> f16 ----------------
__global__ __launch_bounds__(256) void prep_kernel(
    const float* __restrict__ hs, const float* __restrict__ w1,
    const float* __restrict__ b1,
    __half* __restrict__ aH, __half* __restrict__ cH) {
  __shared__ float4 hs4s[16][16];

  const int t  = threadIdx.x;
  const int r0 = blockIdx.x * 16;
  const int hout0 = blockIdx.y * 32;

  {
    const int rr = t >> 4, ff = t & 15;
    hs4s[rr][ff ^ rr] = ((const float4*)(hs + (size_t)r0 * Fd))[t];
  }
  __syncthreads();

  const int r  = t & 15;
  const int hl = (t >> 4) * 2;
  const bool isA = (hout0 < Hd);
  const int hA = hout0 + hl - (isA ? 0 : Hd);
  const float* w1base = w1 + (isA ? 0 : Fd);
  const float4* w1r0 = (const float4*)(w1base + (size_t)(hA + 0) * (2 * Fd));
  const float4* w1r1 = (const float4*)(w1base + (size_t)(hA + 1) * (2 * Fd));

  float acc0 = 0.f, acc1 = 0.f;
#pragma unroll
  for (int f4 = 0; f4 < 16; ++f4) {
    const float4 x  = hs4s[r][f4 ^ r];
    const float4 u0 = w1r0[f4];
    const float4 u1 = w1r1[f4];
    acc0 = fmaf(x.x, u0.x, acc0); acc0 = fmaf(x.y, u0.y, acc0);
    acc0 = fmaf(x.z, u0.z, acc0); acc0 = fmaf(x.w, u0.w, acc0);
    acc1 = fmaf(x.x, u1.x, acc1); acc1 = fmaf(x.y, u1.y, acc1);
    acc1 = fmaf(x.z, u1.z, acc1); acc1 = fmaf(x.w, u1.w, acc1);
  }

  if (isA) {
    acc0 += b1[hA];
    acc1 += b1[hA + 1];
  }
  H2 res;
  res.v = (h2v){(_Float16)acc0, (_Float16)acc1};
  if (isA) *(unsigned int*)(aH + (size_t)(r0 + r) * Hd + hA) = res.u;
  else     *(unsigned int*)(cH + (size_t)(r0 + r) * Hd + hA) = res.u;
}

// ---------------- pair: 64x64 tile, 256 threads, 4x4 outputs/thread, f16 ----------------
// LDS rows = 64 halfs = 8 uint4 chunks; chunk swizzle q ^ ((row>>2)&7):
//   staging writes, aa-reads, cc-reads all land 8 lanes / bank-quad (free).
__global__ __launch_bounds__(256) void pair_kernel(
    const __half* __restrict__ aH, const __half* __restrict__ cH,
    const float* __restrict__ w2, const float* __restrict__ b2,
    float* __restrict__ out) {
  __shared__ uint4 aT[64][8];     // 4 KB
  __shared__ uint4 cT[64][8];     // 4 KB
  __shared__ unsigned int w2h[32];

  const int t  = threadIdx.x;
  const int b  = blockIdx.z;
  const int i0 = blockIdx.y * 64;
  const int j0 = blockIdx.x * 64;

  // stage both 64x64 f16 tiles (512 chunks each), coalesced, swizzled
#pragma unroll
  for (int p = 0; p < 2; ++p) {
    const int k = t + 256 * p;        // 0..511
    const int r = k >> 3, q = k & 7;
    const int sq = q ^ ((r >> 2) & 7);
    aT[r][sq] = ((const uint4*)(aH + (size_t)(b * Nn + i0) * Hd))[k];
    cT[r][sq] = ((const uint4*)(cH + (size_t)(b * Nn + j0) * Hd))[k];
  }
  if (t < 32) {
    H2 w;
    w.v = (h2v){(_Float16)w2[2 * t], (_Float16)w2[2 * t + 1]};
    w2h[t] = w.u;
  }
  __syncthreads();

  const int jt = t & 15;
  const int it = t >> 4;
  const int ib = it * 4;
  const int jb = jt * 4;
  const int sa = it & 7;     // ((ib+u)>>2)&7 == it&7 for u<4
  const int sc = jt & 7;

  const uint4* w2q = (const uint4*)w2h;   // 8 chunks of 8 halfs

  float acc[4][4] = {{0.f}};

  // preload step 0
  uint4 av[4], cv[4];
#pragma unroll
  for (int u = 0; u < 4; ++u) av[u] = aT[ib + u][0 ^ sa];
#pragma unroll
  for (int v = 0; v < 4; ++v) cv[v] = cT[jb + v][0 ^ sc];

#pragma unroll
  for (int h8 = 0; h8 < 8; ++h8) {
    uint4 nav[4], ncv[4];
    if (h8 < 7) {
      const int n = h8 + 1;
#pragma unroll
      for (int u = 0; u < 4; ++u) nav[u] = aT[ib + u][n ^ sa];
#pragma unroll
      for (int v = 0; v < 4; ++v) ncv[v] = cT[jb + v][n ^ sc];
    }

    const uint4 wwu = w2q[h8];          // wave-uniform broadcast
#pragma unroll
    for (int u = 0; u < 4; ++u) {
      const unsigned au4[4] = {av[u].x, av[u].y, av[u].z, av[u].w};
#pragma unroll
      for (int v = 0; v < 4; ++v) {
        const unsigned cu4[4] = {cv[v].x, cv[v].y, cv[v].z, cv[v].w};
        const unsigned wu4[4] = {wwu.x, wwu.y, wwu.z, wwu.w};
#pragma unroll
        for (int m = 0; m < 4; ++m) {
          H2 za, zc, zw;
          za.u = au4[m]; zc.u = cu4[m]; zw.u = wu4[m];
          // v_pk_add_f16 + v_pk_max_f16
          h2v z = __builtin_elementwise_max(za.v + zc.v, (h2v)(_Float16)0);
#if __has_builtin(__builtin_amdgcn_fdot2)
          acc[u][v] = __builtin_amdgcn_fdot2(z, zw.v, acc[u][v], false);
#else
          acc[u][v] = fmaf((float)z.x, (float)zw.v.x, acc[u][v]);
          acc[u][v] = fmaf((float)z.y, (float)zw.v.y, acc[u][v]);
#endif
        }
      }
    }

    if (h8 < 7) {
#pragma unroll
      for (int u = 0; u < 4; ++u) av[u] = nav[u];
#pragma unroll
      for (int v = 0; v < 4; ++v) cv[v] = ncv[v];
    }
  }

  const float bias2 = b2[0];
#pragma unroll
  for (int u = 0; u < 4; ++u) {
    const int i = i0 + ib + u;
    float4 o;
    o.x = (i == j0 + jb + 0) ? 1.0f : 1.f / (1.f + __expf(-(acc[u][0] + bias2)));
    o.y = (i == j0 + jb + 1) ? 1.0f : 1.f / (1.f + __expf(-(acc[u][1] + bias2)));
    o.z = (i == j0 + jb + 2) ? 1.0f : 1.f / (1.f + __expf(-(acc[u][2] + bias2)));
    o.w = (i == j0 + jb + 3) ? 1.0f : 1.f / (1.f + __expf(-(acc[u][3] + bias2)));
    ((float4*)(out + (size_t)(b * Nn + i) * Nn + j0))[jt] = o;
  }
}

extern "C" void kernel_launch(void* const* d_in, const int* in_sizes, int n_in,
                              void* d_out, int out_size, void* d_ws, size_t ws_size,
                              hipStream_t stream) {
  const float* hs = (const float*)d_in[0];
  const float* w1 = (const float*)d_in[1];
  const float* b1 = (const float*)d_in[2];
  const float* w2 = (const float*)d_in[3];
  const float* b2 = (const float*)d_in[4];
  float* out = (float*)d_out;

  __half* aH = (__half*)d_ws;                  // 4096*64 halfs = 512 KB
  __half* cH = aH + (size_t)4096 * Hd;         // 512 KB

  dim3 pgrid(4096 / 16, 4);                    // 1024 blocks
  prep_kernel<<<pgrid, 256, 0, stream>>>(hs, w1, b1, aH, cH);

  dim3 qgrid(Nn / 64, Nn / 64, 16);            // 256 blocks
  pair_kernel<<<qgrid, 256, 0, stream>>>(aH, cH, w2, b2, out);
}

// Round 12
// 17.570 us; speedup vs baseline: 4.7941x; 1.0920x over previous
//
#include <hip/hip_runtime.h>
#include <hip/hip_bf16.h>
#include <hip/hip_fp16.h>

// Problem: B=16, N=256, F=64, H=64
// out[b,i,j] = (i==j) ? 1 : sigmoid( sum_h relu(a[b,i,h]+c[b,j,h]) * w2[h] + b2 )
// a = hs @ w1[:, :64]^T + b1, c = hs @ w1[:, 64:]^T
//
// Round-12: identical math to r11 (f16 pair path). ONE structural change:
// replace fully-unrolled straight-line bodies (~12-24 KB cold I-cache code,
// executed once -> every line a cold fetch miss; fits VALUBusy=26% w/ zero
// mem ops in flight) with short hot loops (#pragma unroll 2 / 4).

#define Nn 256
#define Fd 64
#define Hd 64

typedef _Float16 h2v __attribute__((ext_vector_type(2)));
union H2 { h2v v; unsigned int u; };

// ---------------- prep: a = hs@w1a^T + b1, c = hs@w1c^T -> f16 ----------------
__global__ __launch_bounds__(256) void prep_kernel(
    const float* __restrict__ hs, const float* __restrict__ w1,
    const float* __restrict__ b1,
    __half* __restrict__ aH, __half* __restrict__ cH) {
  __shared__ float4 hs4s[16][16];

  const int t  = threadIdx.x;
  const int r0 = blockIdx.x * 16;
  const int hout0 = blockIdx.y * 32;

  {
    const int rr = t >> 4, ff = t & 15;
    hs4s[rr][ff ^ rr] = ((const float4*)(hs + (size_t)r0 * Fd))[t];
  }
  __syncthreads();

  const int r  = t & 15;
  const int hl = (t >> 4) * 2;
  const bool isA = (hout0 < Hd);
  const int hA = hout0 + hl - (isA ? 0 : Hd);
  const float* w1base = w1 + (isA ? 0 : Fd);
  const float4* w1r0 = (const float4*)(w1base + (size_t)(hA + 0) * (2 * Fd));
  const float4* w1r1 = (const float4*)(w1base + (size_t)(hA + 1) * (2 * Fd));

  float acc0 = 0.f, acc1 = 0.f;
#pragma unroll 4
  for (int f4 = 0; f4 < 16; ++f4) {
    const float4 x  = hs4s[r][f4 ^ r];
    const float4 u0 = w1r0[f4];
    const float4 u1 = w1r1[f4];
    acc0 = fmaf(x.x, u0.x, acc0); acc0 = fmaf(x.y, u0.y, acc0);
    acc0 = fmaf(x.z, u0.z, acc0); acc0 = fmaf(x.w, u0.w, acc0);
    acc1 = fmaf(x.x, u1.x, acc1); acc1 = fmaf(x.y, u1.y, acc1);
    acc1 = fmaf(x.z, u1.z, acc1); acc1 = fmaf(x.w, u1.w, acc1);
  }

  if (isA) {
    acc0 += b1[hA];
    acc1 += b1[hA + 1];
  }
  H2 res;
  res.v = (h2v){(_Float16)acc0, (_Float16)acc1};
  if (isA) *(unsigned int*)(aH + (size_t)(r0 + r) * Hd + hA) = res.u;
  else     *(unsigned int*)(cH + (size_t)(r0 + r) * Hd + hA) = res.u;
}

// ---------------- pair: 64x64 tile, 256 threads, 4x4 outputs/thread, f16 ----------------
// LDS rows = 64 halfs = 8 uint4 chunks; chunk swizzle q ^ ((row>>2)&7):
// staging writes, aa-reads, cc-reads all land 8 lanes / bank-quad (free).
__global__ __launch_bounds__(256) void pair_kernel(
    const __half* __restrict__ aH, const __half* __restrict__ cH,
    const float* __restrict__ w2, const float* __restrict__ b2,
    float* __restrict__ out) {
  __shared__ uint4 aT[64][8];     // 4 KB
  __shared__ uint4 cT[64][8];     // 4 KB
  __shared__ unsigned int w2h[32];

  const int t  = threadIdx.x;
  const int b  = blockIdx.z;
  const int i0 = blockIdx.y * 64;
  const int j0 = blockIdx.x * 64;

  // stage both 64x64 f16 tiles (512 chunks each), coalesced, swizzled
#pragma unroll
  for (int p = 0; p < 2; ++p) {
    const int k = t + 256 * p;        // 0..511
    const int r = k >> 3, q = k & 7;
    const int sq = q ^ ((r >> 2) & 7);
    aT[r][sq] = ((const uint4*)(aH + (size_t)(b * Nn + i0) * Hd))[k];
    cT[r][sq] = ((const uint4*)(cH + (size_t)(b * Nn + j0) * Hd))[k];
  }
  if (t < 32) {
    H2 w;
    w.v = (h2v){(_Float16)w2[2 * t], (_Float16)w2[2 * t + 1]};
    w2h[t] = w.u;
  }
  __syncthreads();

  const int jt = t & 15;
  const int it = t >> 4;
  const int ib = it * 4;
  const int jb = jt * 4;
  const int sa = it & 7;     // ((ib+u)>>2)&7 == it&7 for u<4
  const int sc = jt & 7;

  const uint4* w2q = (const uint4*)w2h;   // 8 chunks of 8 halfs

  float acc[4][4] = {{0.f}};

  // short hot loop: body ~200 instr, I-cache-resident after iter 0
#pragma unroll 2
  for (int h8 = 0; h8 < 8; ++h8) {
    const uint4 wwu = w2q[h8];
    uint4 av[4], cv[4];
#pragma unroll
    for (int u = 0; u < 4; ++u) av[u] = aT[ib + u][h8 ^ sa];
#pragma unroll
    for (int v = 0; v < 4; ++v) cv[v] = cT[jb + v][h8 ^ sc];

#pragma unroll
    for (int u = 0; u < 4; ++u) {
      const unsigned au4[4] = {av[u].x, av[u].y, av[u].z, av[u].w};
#pragma unroll
      for (int v = 0; v < 4; ++v) {
        const unsigned cu4[4] = {cv[v].x, cv[v].y, cv[v].z, cv[v].w};
        const unsigned wu4[4] = {wwu.x, wwu.y, wwu.z, wwu.w};
#pragma unroll
        for (int m = 0; m < 4; ++m) {
          H2 za, zc, zw;
          za.u = au4[m]; zc.u = cu4[m]; zw.u = wu4[m];
          // v_pk_add_f16 + v_pk_max_f16
          h2v z = __builtin_elementwise_max(za.v + zc.v, (h2v)(_Float16)0);
#if __has_builtin(__builtin_amdgcn_fdot2)
          acc[u][v] = __builtin_amdgcn_fdot2(z, zw.v, acc[u][v], false);
#else
          acc[u][v] = fmaf((float)z.x, (float)zw.v.x, acc[u][v]);
          acc[u][v] = fmaf((float)z.y, (float)zw.v.y, acc[u][v]);
#endif
        }
      }
    }
  }

  const float bias2 = b2[0];
#pragma unroll
  for (int u = 0; u < 4; ++u) {
    const int i = i0 + ib + u;
    float4 o;
    o.x = (i == j0 + jb + 0) ? 1.0f : 1.f / (1.f + __expf(-(acc[u][0] + bias2)));
    o.y = (i == j0 + jb + 1) ? 1.0f : 1.f / (1.f + __expf(-(acc[u][1] + bias2)));
    o.z = (i == j0 + jb + 2) ? 1.0f : 1.f / (1.f + __expf(-(acc[u][2] + bias2)));
    o.w = (i == j0 + jb + 3) ? 1.0f : 1.f / (1.f + __expf(-(acc[u][3] + bias2)));
    ((float4*)(out + (size_t)(b * Nn + i) * Nn + j0))[jt] = o;
  }
}

extern "C" void kernel_launch(void* const* d_in, const int* in_sizes, int n_in,
                              void* d_out, int out_size, void* d_ws, size_t ws_size,
                              hipStream_t stream) {
  const float* hs = (const float*)d_in[0];
  const float* w1 = (const float*)d_in[1];
  const float* b1 = (const float*)d_in[2];
  const float* w2 = (const float*)d_in[3];
  const float* b2 = (const float*)d_in[4];
  float* out = (float*)d_out;

  __half* aH = (__half*)d_ws;                  // 4096*64 halfs = 512 KB
  __half* cH = aH + (size_t)4096 * Hd;         // 512 KB

  dim3 pgrid(4096 / 16, 4);                    // 1024 blocks
  prep_kernel<<<pgrid, 256, 0, stream>>>(hs, w1, b1, aH, cH);

  dim3 qgrid(Nn / 64, Nn / 64, 16);            // 256 blocks
  pair_kernel<<<qgrid, 256, 0, stream>>>(aH, cH, w2, b2, out);
}

// Round 14
// 16.509 us; speedup vs baseline: 5.1024x; 1.0643x over previous
//
#include <hip/hip_runtime.h>
#include <hip/hip_bf16.h>
#include <hip/hip_fp16.h>

// Problem: B=16, N=256, F=64, H=64
// out[b,i,j] = (i==j) ? 1 : sigmoid( sum_h relu(a[b,i,h]+c[b,j,h]) * w2[h] + b2 )
// a = hs @ w1[:, :64]^T + b1, c = hs @ w1[:, 64:]^T
//
// Round-14: r13 (MFMA prep) with the cvt_pkrtz type clash fixed
// (builtin returns __fp16x2; bit-land it through the union).

#define Nn 256
#define Fd 64
#define Hd 64

typedef _Float16 h2v  __attribute__((ext_vector_type(2)));
typedef __fp16   fp16x2 __attribute__((ext_vector_type(2)));
typedef _Float16 f16x8 __attribute__((ext_vector_type(8)));
typedef float    f32x4 __attribute__((ext_vector_type(4)));
union H2   { h2v v; fp16x2 p; unsigned int u; };
union U4F8 { uint4 u; f16x8 v; };
union HS1  { _Float16 h; unsigned short s; };

// ---------------- prep (MFMA): [aH|cH] = f16( hs @ [w1a|w1c]^T (+b1) ) ----------------
// 256 blocks x 256 thr. Block = 16 rows x 128 cols. Wave w -> col-tiles 2w,2w+1.
__global__ __launch_bounds__(256) void prep_kernel(
    const float* __restrict__ hs, const float* __restrict__ w1,
    const float* __restrict__ b1,
    __half* __restrict__ aH, __half* __restrict__ cH) {
  __shared__ uint2 w1s[64][32];  // 16 KB: row h, 16 chunks of 8 f16, chunk c at c^(h&15)
  __shared__ uint2 hss[16][16];  //  2 KB: row r,  8 chunks of 8 f16, chunk c at c^(r&7)

  const int t  = threadIdx.x;
  const int r0 = blockIdx.x * 16;

  // stage w1 (64x128 f32 -> f16), coalesced
  {
    const float4* w14 = (const float4*)w1;
#pragma unroll
    for (int p = 0; p < 8; ++p) {
      const int k4 = p * 256 + t;            // 0..2047
      const int r = k4 >> 5, col4 = k4 & 31;
      const float4 v = w14[k4];
      H2 lo, hi;
      lo.p = __builtin_amdgcn_cvt_pkrtz(v.x, v.y);
      hi.p = __builtin_amdgcn_cvt_pkrtz(v.z, v.w);
      const int cc = col4 >> 1, hf = col4 & 1;
      w1s[r][((cc ^ (r & 15)) << 1) | hf] = make_uint2(lo.u, hi.u);
    }
  }
  // stage hs rows r0..r0+15 (16x64 f32 -> f16), coalesced
  {
    const float4* hs4 = (const float4*)(hs + (size_t)r0 * Fd);
    const int r = t >> 4, col4 = t & 15;
    const float4 v = hs4[t];
    H2 lo, hi;
    lo.p = __builtin_amdgcn_cvt_pkrtz(v.x, v.y);
    hi.p = __builtin_amdgcn_cvt_pkrtz(v.z, v.w);
    const int cc = col4 >> 1, hf = col4 & 1;
    hss[r][((cc ^ (r & 7)) << 1) | hf] = make_uint2(lo.u, hi.u);
  }
  __syncthreads();

  const int l   = t & 63;
  const int w   = t >> 6;        // wave 0..3
  const int l15 = l & 15, l4 = l >> 4;

  f32x4 acc[2] = {{0.f, 0.f, 0.f, 0.f}, {0.f, 0.f, 0.f, 0.f}};

#pragma unroll
  for (int s = 0; s < 2; ++s) {
    // A-frag: A[m=l15][k=(l4)*8+i + 32*s], contiguous 8 f16 -> one b128
    U4F8 af;
    af.u = ((const uint4*)&hss[l15][0])[(s * 4 + l4) ^ (l15 & 7)];
#pragma unroll
    for (int tt = 0; tt < 2; ++tt) {
      const int tn = 2 * w + tt;
      const int n  = tn * 16 + l15;           // output col 0..127
      const int rh = n & 63;                  // w1 row
      const int cc = ((n >> 6) << 3) + s * 4 + l4;  // chunk in w1 row
      U4F8 bf;
      bf.u = ((const uint4*)&w1s[rh][0])[cc ^ (rh & 15)];
      acc[tt] = __builtin_amdgcn_mfma_f32_16x16x32_f16(af.v, bf.v, acc[tt], 0, 0, 0);
    }
  }

#pragma unroll
  for (int tt = 0; tt < 2; ++tt) {
    const int n = (2 * w + tt) * 16 + l15;
    const float bval = (n < Hd) ? b1[n] : 0.f;
    unsigned short* dst = (n < Hd) ? (unsigned short*)aH : (unsigned short*)cH;
    const int ncol = n & 63;
#pragma unroll
    for (int i = 0; i < 4; ++i) {
      const int row = r0 + l4 * 4 + i;        // C/D: row=(lane>>4)*4+reg (m89)
      HS1 x; x.h = (_Float16)(acc[tt][i] + bval);
      dst[(size_t)row * Hd + ncol] = x.s;
    }
  }
}

// ---------------- pair: r12 verbatim (64x64 tile, 256 thr, f16, unroll 2) ----------------
__global__ __launch_bounds__(256) void pair_kernel(
    const __half* __restrict__ aH, const __half* __restrict__ cH,
    const float* __restrict__ w2, const float* __restrict__ b2,
    float* __restrict__ out) {
  __shared__ uint4 aT[64][8];     // 4 KB
  __shared__ uint4 cT[64][8];     // 4 KB
  __shared__ unsigned int w2h[32];

  const int t  = threadIdx.x;
  const int b  = blockIdx.z;
  const int i0 = blockIdx.y * 64;
  const int j0 = blockIdx.x * 64;

#pragma unroll
  for (int p = 0; p < 2; ++p) {
    const int k = t + 256 * p;        // 0..511
    const int r = k >> 3, q = k & 7;
    const int sq = q ^ ((r >> 2) & 7);
    aT[r][sq] = ((const uint4*)(aH + (size_t)(b * Nn + i0) * Hd))[k];
    cT[r][sq] = ((const uint4*)(cH + (size_t)(b * Nn + j0) * Hd))[k];
  }
  if (t < 32) {
    H2 wv2;
    wv2.v = (h2v){(_Float16)w2[2 * t], (_Float16)w2[2 * t + 1]};
    w2h[t] = wv2.u;
  }
  __syncthreads();

  const int jt = t & 15;
  const int it = t >> 4;
  const int ib = it * 4;
  const int jb = jt * 4;
  const int sa = it & 7;
  const int sc = jt & 7;

  const uint4* w2q = (const uint4*)w2h;

  float acc[4][4] = {{0.f}};

#pragma unroll 2
  for (int h8 = 0; h8 < 8; ++h8) {
    const uint4 wwu = w2q[h8];
    uint4 av[4], cv[4];
#pragma unroll
    for (int u = 0; u < 4; ++u) av[u] = aT[ib + u][h8 ^ sa];
#pragma unroll
    for (int v = 0; v < 4; ++v) cv[v] = cT[jb + v][h8 ^ sc];

#pragma unroll
    for (int u = 0; u < 4; ++u) {
      const unsigned au4[4] = {av[u].x, av[u].y, av[u].z, av[u].w};
#pragma unroll
      for (int v = 0; v < 4; ++v) {
        const unsigned cu4[4] = {cv[v].x, cv[v].y, cv[v].z, cv[v].w};
        const unsigned wu4[4] = {wwu.x, wwu.y, wwu.z, wwu.w};
#pragma unroll
        for (int m = 0; m < 4; ++m) {
          H2 za, zc, zw;
          za.u = au4[m]; zc.u = cu4[m]; zw.u = wu4[m];
          h2v z = __builtin_elementwise_max(za.v + zc.v, (h2v)(_Float16)0);
#if __has_builtin(__builtin_amdgcn_fdot2)
          acc[u][v] = __builtin_amdgcn_fdot2(z, zw.v, acc[u][v], false);
#else
          acc[u][v] = fmaf((float)z.x, (float)zw.v.x, acc[u][v]);
          acc[u][v] = fmaf((float)z.y, (float)zw.v.y, acc[u][v]);
#endif
        }
      }
    }
  }

  const float bias2 = b2[0];
#pragma unroll
  for (int u = 0; u < 4; ++u) {
    const int i = i0 + ib + u;
    float4 o;
    o.x = (i == j0 + jb + 0) ? 1.0f : 1.f / (1.f + __expf(-(acc[u][0] + bias2)));
    o.y = (i == j0 + jb + 1) ? 1.0f : 1.f / (1.f + __expf(-(acc[u][1] + bias2)));
    o.z = (i == j0 + jb + 2) ? 1.0f : 1.f / (1.f + __expf(-(acc[u][2] + bias2)));
    o.w = (i == j0 + jb + 3) ? 1.0f : 1.f / (1.f + __expf(-(acc[u][3] + bias2)));
    ((float4*)(out + (size_t)(b * Nn + i) * Nn + j0))[jt] = o;
  }
}

extern "C" void kernel_launch(void* const* d_in, const int* in_sizes, int n_in,
                              void* d_out, int out_size, void* d_ws, size_t ws_size,
                              hipStream_t stream) {
  const float* hs = (const float*)d_in[0];
  const float* w1 = (const float*)d_in[1];
  const float* b1 = (const float*)d_in[2];
  const float* w2 = (const float*)d_in[3];
  const float* b2 = (const float*)d_in[4];
  float* out = (float*)d_out;

  __half* aH = (__half*)d_ws;                  // 4096*64 halfs = 512 KB
  __half* cH = aH + (size_t)4096 * Hd;         // 512 KB

  prep_kernel<<<4096 / 16, 256, 0, stream>>>(hs, w1, b1, aH, cH);

  dim3 qgrid(Nn / 64, Nn / 64, 16);            // 256 blocks
  pair_kernel<<<qgrid, 256, 0, stream>>>(aH, cH, w2, b2, out);
}

// Round 15
// 13.040 us; speedup vs baseline: 6.4595x; 1.2660x over previous
//
#include <hip/hip_runtime.h>
#include <hip/hip_bf16.h>
#include <hip/hip_fp16.h>

// Problem: B=16, N=256, F=64, H=64
// out[b,i,j] = (i==j) ? 1 : sigmoid( sum_h relu(a[b,i,h]+c[b,j,h]) * w2[h] + b2 )
// a = hs @ w1[:, :64]^T + b1, c = hs @ w1[:, 64:]^T
//
// Round-15: single fused kernel. Phase-1 = MFMA a/c tile computation in-LDS
// (r14's verified fragment pattern; x4 redundancy is MFMA-cheap, staging is
// coalesced -- unlike r7's failed scalar-gather fusion). Phase-2 = r12 pair
// body verbatim. Kills prep launch, prep epilogue, and pair's exposed-latency
// cross-XCD global staging of a/c.

#define Nn 256
#define Fd 64
#define Hd 64

typedef _Float16 h2v    __attribute__((ext_vector_type(2)));
typedef __fp16   fp16x2 __attribute__((ext_vector_type(2)));
typedef _Float16 f16x8  __attribute__((ext_vector_type(8)));
typedef float    f32x4  __attribute__((ext_vector_type(4)));
union H2   { h2v v; fp16x2 p; unsigned int u; };
union U4F8 { uint4 u; f16x8 v; };
union HS1  { _Float16 h; unsigned short s; };

__global__ __launch_bounds__(256) void fused_kernel(
    const float* __restrict__ hs, const float* __restrict__ w1,
    const float* __restrict__ b1, const float* __restrict__ w2,
    const float* __restrict__ b2, float* __restrict__ out) {
  __shared__ uint2 w1s[64][32];   // 16 KB: w1 f16, row h, chunk c at c^(h&15)
  __shared__ uint2 hsI[64][16];   //  8 KB: hs i-rows f16, chunk c at c^(r&7)
  __shared__ uint2 hsJ[64][16];   //  8 KB: hs j-rows f16
  __shared__ uint4 aT[64][8];     //  4 KB: a-tile f16 (pair layout)
  __shared__ uint4 cT[64][8];     //  4 KB: c-tile f16
  __shared__ unsigned int w2h[32];

  const int t  = threadIdx.x;
  const int b  = blockIdx.z;
  const int i0 = blockIdx.y * 64;
  const int j0 = blockIdx.x * 64;

  // ---- stage w1 (64x128 f32 -> f16 LDS), coalesced ----
  {
    const float4* w14 = (const float4*)w1;
#pragma unroll
    for (int p = 0; p < 8; ++p) {
      const int k4 = p * 256 + t;            // 0..2047
      const int r = k4 >> 5, col4 = k4 & 31;
      const float4 v = w14[k4];
      H2 lo, hi;
      lo.p = __builtin_amdgcn_cvt_pkrtz(v.x, v.y);
      hi.p = __builtin_amdgcn_cvt_pkrtz(v.z, v.w);
      const int cc = col4 >> 1, hf = col4 & 1;
      w1s[r][((cc ^ (r & 15)) << 1) | hf] = make_uint2(lo.u, hi.u);
    }
  }
  // ---- stage hs i-rows and j-rows (64x64 f32 -> f16), coalesced ----
  {
    const float4* hi4 = (const float4*)(hs + (size_t)(b * Nn + i0) * Fd);
    const float4* hj4 = (const float4*)(hs + (size_t)(b * Nn + j0) * Fd);
#pragma unroll
    for (int p = 0; p < 4; ++p) {
      const int k4 = p * 256 + t;            // 0..1023
      const int r = k4 >> 4, col4 = k4 & 15;
      const int cc = col4 >> 1, hf = col4 & 1;
      const int idx = ((cc ^ (r & 7)) << 1) | hf;
      {
        const float4 v = hi4[k4];
        H2 lo, hi_;
        lo.p  = __builtin_amdgcn_cvt_pkrtz(v.x, v.y);
        hi_.p = __builtin_amdgcn_cvt_pkrtz(v.z, v.w);
        hsI[r][idx] = make_uint2(lo.u, hi_.u);
      }
      {
        const float4 v = hj4[k4];
        H2 lo, hi_;
        lo.p  = __builtin_amdgcn_cvt_pkrtz(v.x, v.y);
        hi_.p = __builtin_amdgcn_cvt_pkrtz(v.z, v.w);
        hsJ[r][idx] = make_uint2(lo.u, hi_.u);
      }
    }
  }
  if (t < 32) {
    H2 wv2;
    wv2.v = (h2v){(_Float16)w2[2 * t], (_Float16)w2[2 * t + 1]};
    w2h[t] = wv2.u;
  }
  __syncthreads();

  // ---- phase 1: MFMA. wave w -> rows 16w..16w+15; 4 n-tiles a + 4 n-tiles c ----
  {
    const int l   = t & 63;
    const int w   = t >> 6;
    const int l15 = l & 15, l4 = l >> 4;
    const int mrow = w * 16 + l15;            // A-frag row (m = l15 within tile)

    f32x4 acca[4] = {{0,0,0,0},{0,0,0,0},{0,0,0,0},{0,0,0,0}};
    f32x4 accc[4] = {{0,0,0,0},{0,0,0,0},{0,0,0,0},{0,0,0,0}};

#pragma unroll
    for (int s = 0; s < 2; ++s) {
      U4F8 afI, afJ;
      afI.u = ((const uint4*)&hsI[mrow][0])[(s * 4 + l4) ^ (mrow & 7)];
      afJ.u = ((const uint4*)&hsJ[mrow][0])[(s * 4 + l4) ^ (mrow & 7)];
#pragma unroll
      for (int nt = 0; nt < 4; ++nt) {
        const int rh = nt * 16 + l15;         // w1 row = output h (B-frag row)
        U4F8 bfa, bfc;
        bfa.u = ((const uint4*)&w1s[rh][0])[(s * 4 + l4) ^ (rh & 15)];
        bfc.u = ((const uint4*)&w1s[rh][0])[(8 + s * 4 + l4) ^ (rh & 15)];
        acca[nt] = __builtin_amdgcn_mfma_f32_16x16x32_f16(afI.v, bfa.v, acca[nt], 0, 0, 0);
        accc[nt] = __builtin_amdgcn_mfma_f32_16x16x32_f16(afJ.v, bfc.v, accc[nt], 0, 0, 0);
      }
    }

    __syncthreads();   // hsI/hsJ reads done (aT/cT are separate arrays, but keep order clean)

    // epilogue: write a/c tiles (f16) into pair-layout LDS
    unsigned short* aTh = (unsigned short*)aT;
    unsigned short* cTh = (unsigned short*)cT;
#pragma unroll
    for (int nt = 0; nt < 4; ++nt) {
      const int n = nt * 16 + l15;            // h col 0..63
      const float bval = b1[n];
      const int chunk = n >> 3, pos = n & 7;
#pragma unroll
      for (int i = 0; i < 4; ++i) {
        const int row = w * 16 + l4 * 4 + i;  // C/D: row=(lane>>4)*4+reg (verified)
        const int sw = chunk ^ ((row >> 2) & 7);
        HS1 xa; xa.h = (_Float16)(acca[nt][i] + bval);
        aTh[row * 64 + sw * 8 + pos] = xa.s;
        HS1 xc; xc.h = (_Float16)(accc[nt][i]);
        cTh[row * 64 + sw * 8 + pos] = xc.s;
      }
    }
  }
  __syncthreads();

  // ---- phase 2: pair body (r12 verbatim) ----
  const int jt = t & 15;
  const int it = t >> 4;
  const int ib = it * 4;
  const int jb = jt * 4;
  const int sa = it & 7;
  const int sc = jt & 7;

  const uint4* w2q = (const uint4*)w2h;

  float acc[4][4] = {{0.f}};

#pragma unroll 2
  for (int h8 = 0; h8 < 8; ++h8) {
    const uint4 wwu = w2q[h8];
    uint4 av[4], cv[4];
#pragma unroll
    for (int u = 0; u < 4; ++u) av[u] = aT[ib + u][h8 ^ sa];
#pragma unroll
    for (int v = 0; v < 4; ++v) cv[v] = cT[jb + v][h8 ^ sc];

#pragma unroll
    for (int u = 0; u < 4; ++u) {
      const unsigned au4[4] = {av[u].x, av[u].y, av[u].z, av[u].w};
#pragma unroll
      for (int v = 0; v < 4; ++v) {
        const unsigned cu4[4] = {cv[v].x, cv[v].y, cv[v].z, cv[v].w};
        const unsigned wu4[4] = {wwu.x, wwu.y, wwu.z, wwu.w};
#pragma unroll
        for (int m = 0; m < 4; ++m) {
          H2 za, zc, zw;
          za.u = au4[m]; zc.u = cu4[m]; zw.u = wu4[m];
          h2v z = __builtin_elementwise_max(za.v + zc.v, (h2v)(_Float16)0);
#if __has_builtin(__builtin_amdgcn_fdot2)
          acc[u][v] = __builtin_amdgcn_fdot2(z, zw.v, acc[u][v], false);
#else
          acc[u][v] = fmaf((float)z.x, (float)zw.v.x, acc[u][v]);
          acc[u][v] = fmaf((float)z.y, (float)zw.v.y, acc[u][v]);
#endif
        }
      }
    }
  }

  const float bias2 = b2[0];
#pragma unroll
  for (int u = 0; u < 4; ++u) {
    const int i = i0 + ib + u;
    float4 o;
    o.x = (i == j0 + jb + 0) ? 1.0f : 1.f / (1.f + __expf(-(acc[u][0] + bias2)));
    o.y = (i == j0 + jb + 1) ? 1.0f : 1.f / (1.f + __expf(-(acc[u][1] + bias2)));
    o.z = (i == j0 + jb + 2) ? 1.0f : 1.f / (1.f + __expf(-(acc[u][2] + bias2)));
    o.w = (i == j0 + jb + 3) ? 1.0f : 1.f / (1.f + __expf(-(acc[u][3] + bias2)));
    ((float4*)(out + (size_t)(b * Nn + i) * Nn + j0))[jt] = o;
  }
}

extern "C" void kernel_launch(void* const* d_in, const int* in_sizes, int n_in,
                              void* d_out, int out_size, void* d_ws, size_t ws_size,
                              hipStream_t stream) {
  const float* hs = (const float*)d_in[0];
  const float* w1 = (const float*)d_in[1];
  const float* b1 = (const float*)d_in[2];
  const float* w2 = (const float*)d_in[3];
  const float* b2 = (const float*)d_in[4];
  float* out = (float*)d_out;

  dim3 grid(Nn / 64, Nn / 64, 16);   // (j-tiles, i-tiles, b) = 256 blocks
  fused_kernel<<<grid, 256, 0, stream>>>(hs, w1, b1, w2, b2, out);
}

// Round 16
// 12.064 us; speedup vs baseline: 6.9825x; 1.0810x over previous
//
#include <hip/hip_runtime.h>
#include <hip/hip_bf16.h>
#include <hip/hip_fp16.h>

// Problem: B=16, N=256, F=64, H=64
// out[b,i,j] = (i==j) ? 1 : sigmoid( sum_h relu(a[b,i,h]+c[b,j,h]) * w2[h] + b2 )
// a = hs @ w1[:, :64]^T + b1, c = hs @ w1[:, 64:]^T
//
// Round-16: r15 fused kernel at 512 threads/block (8 waves -> 2 waves/SIMD).
// Phase-1 balanced: waves 0-3 compute the a-tile, waves 4-7 the c-tile
// (8 MFMA each). Phase-2: 8 outputs/thread (2x4). f16 path keeps VGPR ~60
// (no r8-style spill at the 128 cap). Mid-phase __syncthreads removed.

#define Nn 256
#define Fd 64
#define Hd 64

typedef _Float16 h2v    __attribute__((ext_vector_type(2)));
typedef __fp16   fp16x2 __attribute__((ext_vector_type(2)));
typedef _Float16 f16x8  __attribute__((ext_vector_type(8)));
typedef float    f32x4  __attribute__((ext_vector_type(4)));
union H2   { h2v v; fp16x2 p; unsigned int u; };
union U4F8 { uint4 u; f16x8 v; };
union HS1  { _Float16 h; unsigned short s; };

__global__ __launch_bounds__(512) void fused_kernel(
    const float* __restrict__ hs, const float* __restrict__ w1,
    const float* __restrict__ b1, const float* __restrict__ w2,
    const float* __restrict__ b2, float* __restrict__ out) {
  __shared__ uint2 w1s[64][32];   // 16 KB: w1 f16, row h, chunk c at c^(h&15)
  __shared__ uint2 hsI[64][16];   //  8 KB: hs i-rows f16, chunk c at c^(r&7)
  __shared__ uint2 hsJ[64][16];   //  8 KB: hs j-rows f16
  __shared__ uint4 aT[64][8];     //  4 KB: a-tile f16 (pair layout)
  __shared__ uint4 cT[64][8];     //  4 KB: c-tile f16
  __shared__ unsigned int w2h[32];

  const int t  = threadIdx.x;
  const int b  = blockIdx.z;
  const int i0 = blockIdx.y * 64;
  const int j0 = blockIdx.x * 64;

  // ---- stage w1 (64x128 f32 -> f16 LDS), coalesced ----
  {
    const float4* w14 = (const float4*)w1;
#pragma unroll
    for (int p = 0; p < 4; ++p) {
      const int k4 = p * 512 + t;            // 0..2047
      const int r = k4 >> 5, col4 = k4 & 31;
      const float4 v = w14[k4];
      H2 lo, hi;
      lo.p = __builtin_amdgcn_cvt_pkrtz(v.x, v.y);
      hi.p = __builtin_amdgcn_cvt_pkrtz(v.z, v.w);
      const int cc = col4 >> 1, hf = col4 & 1;
      w1s[r][((cc ^ (r & 15)) << 1) | hf] = make_uint2(lo.u, hi.u);
    }
  }
  // ---- stage hs i-rows and j-rows (64x64 f32 -> f16), coalesced ----
  {
    const float4* hi4 = (const float4*)(hs + (size_t)(b * Nn + i0) * Fd);
    const float4* hj4 = (const float4*)(hs + (size_t)(b * Nn + j0) * Fd);
#pragma unroll
    for (int p = 0; p < 2; ++p) {
      const int k4 = p * 512 + t;            // 0..1023
      const int r = k4 >> 4, col4 = k4 & 15;
      const int cc = col4 >> 1, hf = col4 & 1;
      const int idx = ((cc ^ (r & 7)) << 1) | hf;
      {
        const float4 v = hi4[k4];
        H2 lo, hi_;
        lo.p  = __builtin_amdgcn_cvt_pkrtz(v.x, v.y);
        hi_.p = __builtin_amdgcn_cvt_pkrtz(v.z, v.w);
        hsI[r][idx] = make_uint2(lo.u, hi_.u);
      }
      {
        const float4 v = hj4[k4];
        H2 lo, hi_;
        lo.p  = __builtin_amdgcn_cvt_pkrtz(v.x, v.y);
        hi_.p = __builtin_amdgcn_cvt_pkrtz(v.z, v.w);
        hsJ[r][idx] = make_uint2(lo.u, hi_.u);
      }
    }
  }
  if (t < 32) {
    H2 wv2;
    wv2.v = (h2v){(_Float16)w2[2 * t], (_Float16)w2[2 * t + 1]};
    w2h[t] = wv2.u;
  }
  __syncthreads();

  // ---- phase 1: MFMA. waves 0-3 -> a-tile rows 16w..; waves 4-7 -> c-tile ----
  {
    const int l   = t & 63;
    const int w   = t >> 6;                  // 0..7
    const bool isA = (w < 4);
    const int wv  = w & 3;
    const int l15 = l & 15, l4 = l >> 4;
    const int mrow = wv * 16 + l15;          // A-frag row

    const uint2 (*hsX)[16] = isA ? hsI : hsJ;
    const int cbase = isA ? 0 : 8;           // w1 chunk base: a cols [0,64), c [64,128)

    f32x4 acc1[4] = {{0,0,0,0},{0,0,0,0},{0,0,0,0},{0,0,0,0}};

#pragma unroll
    for (int s = 0; s < 2; ++s) {
      U4F8 af;
      af.u = ((const uint4*)&hsX[mrow][0])[(s * 4 + l4) ^ (mrow & 7)];
#pragma unroll
      for (int nt = 0; nt < 4; ++nt) {
        const int rh = nt * 16 + l15;        // w1 row = output h
        U4F8 bf;
        bf.u = ((const uint4*)&w1s[rh][0])[(cbase + s * 4 + l4) ^ (rh & 15)];
        acc1[nt] = __builtin_amdgcn_mfma_f32_16x16x32_f16(af.v, bf.v, acc1[nt], 0, 0, 0);
      }
    }

    // epilogue: write tile (f16) into pair-layout LDS (aT/cT separate from hsI/hsJ -> no barrier needed)
    unsigned short* dTh = isA ? (unsigned short*)aT : (unsigned short*)cT;
#pragma unroll
    for (int nt = 0; nt < 4; ++nt) {
      const int n = nt * 16 + l15;           // h col 0..63
      const float bval = isA ? b1[n] : 0.f;
      const int chunk = n >> 3, pos = n & 7;
#pragma unroll
      for (int i = 0; i < 4; ++i) {
        const int row = wv * 16 + l4 * 4 + i;  // C/D: row=(lane>>4)*4+reg (verified r14)
        const int sw = chunk ^ ((row >> 2) & 7);
        HS1 x; x.h = (_Float16)(acc1[nt][i] + bval);
        dTh[row * 64 + sw * 8 + pos] = x.s;
      }
    }
  }
  __syncthreads();

  // ---- phase 2: pair (r12 body at 2x4 outputs/thread) ----
  const int jt  = t & 15;
  const int it2 = t >> 4;        // 0..31
  const int ib  = it2 * 2;
  const int jb  = jt * 4;
  const int sa  = (it2 >> 1) & 7;   // ((ib+u)>>2)&7, uniform for u=0,1
  const int sc  = jt & 7;

  const uint4* w2q = (const uint4*)w2h;

  float acc[2][4] = {{0.f}};

#pragma unroll 2
  for (int h8 = 0; h8 < 8; ++h8) {
    const uint4 wwu = w2q[h8];
    uint4 av[2], cv[4];
#pragma unroll
    for (int u = 0; u < 2; ++u) av[u] = aT[ib + u][h8 ^ sa];
#pragma unroll
    for (int v = 0; v < 4; ++v) cv[v] = cT[jb + v][h8 ^ sc];

#pragma unroll
    for (int u = 0; u < 2; ++u) {
      const unsigned au4[4] = {av[u].x, av[u].y, av[u].z, av[u].w};
#pragma unroll
      for (int v = 0; v < 4; ++v) {
        const unsigned cu4[4] = {cv[v].x, cv[v].y, cv[v].z, cv[v].w};
        const unsigned wu4[4] = {wwu.x, wwu.y, wwu.z, wwu.w};
#pragma unroll
        for (int m = 0; m < 4; ++m) {
          H2 za, zc, zw;
          za.u = au4[m]; zc.u = cu4[m]; zw.u = wu4[m];
          h2v z = __builtin_elementwise_max(za.v + zc.v, (h2v)(_Float16)0);
#if __has_builtin(__builtin_amdgcn_fdot2)
          acc[u][v] = __builtin_amdgcn_fdot2(z, zw.v, acc[u][v], false);
#else
          acc[u][v] = fmaf((float)z.x, (float)zw.v.x, acc[u][v]);
          acc[u][v] = fmaf((float)z.y, (float)zw.v.y, acc[u][v]);
#endif
        }
      }
    }
  }

  const float bias2 = b2[0];
#pragma unroll
  for (int u = 0; u < 2; ++u) {
    const int i = i0 + ib + u;
    float4 o;
    o.x = (i == j0 + jb + 0) ? 1.0f : 1.f / (1.f + __expf(-(acc[u][0] + bias2)));
    o.y = (i == j0 + jb + 1) ? 1.0f : 1.f / (1.f + __expf(-(acc[u][1] + bias2)));
    o.z = (i == j0 + jb + 2) ? 1.0f : 1.f / (1.f + __expf(-(acc[u][2] + bias2)));
    o.w = (i == j0 + jb + 3) ? 1.0f : 1.f / (1.f + __expf(-(acc[u][3] + bias2)));
    ((float4*)(out + (size_t)(b * Nn + i) * Nn + j0))[jt] = o;
  }
}

extern "C" void kernel_launch(void* const* d_in, const int* in_sizes, int n_in,
                              void* d_out, int out_size, void* d_ws, size_t ws_size,
                              hipStream_t stream) {
  const float* hs = (const float*)d_in[0];
  const float* w1 = (const float*)d_in[1];
  const float* b1 = (const float*)d_in[2];
  const float* w2 = (const float*)d_in[3];
  const float* b2 = (const float*)d_in[4];
  float* out = (float*)d_out;

  dim3 grid(Nn / 64, Nn / 64, 16);   // (j-tiles, i-tiles, b) = 256 blocks
  fused_kernel<<<grid, 512, 0, stream>>>(hs, w1, b1, w2, b2, out);
}